// Round 1
// 1159.515 us; speedup vs baseline: 1.0942x; 1.0942x over previous
//
#include <hip/hip_runtime.h>

// ---------------------------------------------------------------------------
// Decoder: B=8 T=512 D=1024 H=16 DH=64 L=4 C=10.
// Round 3: occupancy + fusion pass.
//  - QKV GEMMs fused into one 4096x3072x1024 GEMM (768 blocks = 3/CU,
//    vs 256 blocks = 1/CU before). Weights pre-cast into fused
//    [L][3072][1024] layout; epilogue routes 1024-col segments to the
//    contiguous qbf/kbf/vbf buffers.
//  - fc epilogue (bias+relu+residual) fused into GEMM epilogue (mode 2):
//    removes fc_ep_k launches and the qb32 fp32 round-trip.
//  - all 7 startup casts merged into one kernel (7 segments).
//  - s_setprio(1) around attention MFMA clusters.
// Workspace (120 MB): cur 16 | tmp 16 | act_bf 8 | qkv_bf 24 (q,k,v contig)
//                     | kinbf 8 | vinbf 8 | wqkv 24 | wq2 8 | wfc 8
// ---------------------------------------------------------------------------

#define BB   8
#define TT   512
#define DD   1024
#define HH   16
#define DHH  64
#define LLAY 4
#define MM   (BB*TT)          // 4096 rows
#define MD   ((size_t)MM*DD)  // 4,194,304 elements
#define INV_RD (1.0f/32.0f)   // 1/sqrt(D)
#define LNEPS 1e-5f

typedef unsigned short ushort_t;
typedef __attribute__((ext_vector_type(8))) short short8;
typedef __attribute__((ext_vector_type(4))) float floatx4;

__device__ inline ushort_t f2bf(float f) {
  unsigned u = __builtin_bit_cast(unsigned, f);
  unsigned r = (u + 0x7FFFu + ((u >> 16) & 1u)) >> 16;  // RNE
  return (ushort_t)r;
}

// One kernel, 7 segments of 4M fp32 elements each (1M float4 / segment,
// 4096 blocks / segment):
//  seg 0..2 : Wq1/Wk1/Wv1 [L,1024,1024] -> fused wqkv [L][3072][1024]
//  seg 3,4  : Wq2, Wfc -> linear bf16
//  seg 5,6  : kin, vin -> linear bf16
__global__ __launch_bounds__(256) void cast_all_k(
    const float* __restrict__ Wq1, const float* __restrict__ Wk1,
    const float* __restrict__ Wv1, const float* __restrict__ Wq2f,
    const float* __restrict__ Wfcf, const float* __restrict__ kin,
    const float* __restrict__ vin,
    ushort_t* __restrict__ wqkv, ushort_t* __restrict__ wq2,
    ushort_t* __restrict__ wfc, ushort_t* __restrict__ kinbf,
    ushort_t* __restrict__ vinbf) {
  int seg = blockIdx.x >> 12;
  size_t j = ((size_t)(blockIdx.x & 4095)) * 256 + threadIdx.x;  // float4 idx
  const float* src;
  switch (seg) {
    case 0: src = Wq1; break;
    case 1: src = Wk1; break;
    case 2: src = Wv1; break;
    case 3: src = Wq2f; break;
    case 4: src = Wfcf; break;
    case 5: src = kin; break;
    default: src = vin; break;
  }
  float4 v = ((const float4*)src)[j];
  ushort4 o; o.x = f2bf(v.x); o.y = f2bf(v.y); o.z = f2bf(v.z); o.w = f2bf(v.w);
  if (seg < 3) {
    int d4 = (int)(j & 255);
    int n  = (int)((j >> 8) & 1023);
    int i  = (int)(j >> 18);
    size_t drow = (size_t)i * 3072 + (size_t)seg * 1024 + n;
    ((ushort4*)wqkv)[drow * 256 + d4] = o;
  } else {
    ushort_t* dst = (seg == 3) ? wq2 : (seg == 4) ? wfc : (seg == 5) ? kinbf : vinbf;
    ((ushort4*)dst)[j] = o;
  }
}

// x + pos (pos broadcast over batch); writes fp32 + bf16 copies.
__global__ __launch_bounds__(256) void add_pos_k(const float* __restrict__ x,
                                                 const float* __restrict__ pos,
                                                 float* __restrict__ out,
                                                 ushort_t* __restrict__ out_bf) {
  size_t i = (size_t)blockIdx.x * 256 + threadIdx.x;  // float4 index
  int dq  = (int)(i & 255);
  int row = (int)(i >> 8);
  int t   = row & (TT - 1);
  float4 a = ((const float4*)x)[i];
  float4 p = ((const float4*)pos)[(size_t)t * 256 + dq];
  a.x += p.x; a.y += p.y; a.z += p.z; a.w += p.w;
  ((float4*)out)[i] = a;
  ushort4 b; b.x = f2bf(a.x); b.y = f2bf(a.y); b.z = f2bf(a.z); b.w = f2bf(a.w);
  ((ushort4*)out_bf)[i] = b;
}

// LayerNorm: one block per row of D=1024; writes fp32 + bf16 copies.
__global__ __launch_bounds__(256) void ln_k(const float* __restrict__ in,
                                            float* __restrict__ out,
                                            ushort_t* __restrict__ out_bf,
                                            const float* __restrict__ g,
                                            const float* __restrict__ bt) {
  int row = blockIdx.x;
  int t = threadIdx.x;
  const float4* r4 = (const float4*)(in + (size_t)row * DD);
  float4 v = r4[t];
  float s  = v.x + v.y + v.z + v.w;
  float ss = v.x*v.x + v.y*v.y + v.z*v.z + v.w*v.w;
#pragma unroll
  for (int off = 32; off > 0; off >>= 1) {
    s  += __shfl_down(s, off);
    ss += __shfl_down(ss, off);
  }
  __shared__ float red[8];
  int w = t >> 6;
  if ((t & 63) == 0) { red[w] = s; red[4 + w] = ss; }
  __syncthreads();
  s  = red[0] + red[1] + red[2] + red[3];
  ss = red[4] + red[5] + red[6] + red[7];
  float mean = s * (1.0f / DD);
  float var  = ss * (1.0f / DD) - mean * mean;
  float inv  = rsqrtf(var + LNEPS);
  float4 gv = ((const float4*)g)[t];
  float4 bv = ((const float4*)bt)[t];
  float4 o;
  o.x = (v.x - mean) * inv * gv.x + bv.x;
  o.y = (v.y - mean) * inv * gv.y + bv.y;
  o.z = (v.z - mean) * inv * gv.z + bv.z;
  o.w = (v.w - mean) * inv * gv.w + bv.w;
  ((float4*)(out + (size_t)row * DD))[t] = o;
  ushort4 ob; ob.x = f2bf(o.x); ob.y = f2bf(o.y); ob.z = f2bf(o.z); ob.w = f2bf(o.w);
  ((ushort4*)(out_bf + (size_t)row * DD))[t] = ob;
}

// C[m,n] = sum_k A[m,k]*W[n,k], A/W bf16, 128x128 tile, m97 structure.
// mode 1: bf16 out; output columns are 1024-wide segments routed to
//         contiguous [MM,DD] buffers at Cout + seg*MD  (seg = n0>>10).
//         (N=1024 callers degenerate to seg=0 — same code path.)
// mode 2: fp32 fc epilogue: C = relu(acc + bias[n]) + lnres[m,n].
__global__ __launch_bounds__(256) void gemm_mfma_bt_k(const ushort_t* __restrict__ A,
                                                      const ushort_t* __restrict__ W,
                                                      void* __restrict__ Cout,
                                                      const float* __restrict__ bias,
                                                      const float* __restrict__ lnres,
                                                      int mode) {
  __shared__ ushort_t As[128 * 32];
  __shared__ ushort_t Bs[128 * 32];
  int t = threadIdx.x;
  int n0 = blockIdx.x * 128, m0 = blockIdx.y * 128;
  int lane = t & 63, w = t >> 6;
  int wm = (w >> 1) * 64, wn = (w & 1) * 64;
  int fr = lane & 15, q = lane >> 4;
  const short8* ap[4]; const short8* bp[4];
#pragma unroll
  for (int i = 0; i < 4; i++) {
    int r  = wm + i * 16 + fr;
    int rn = wn + i * 16 + fr;
    ap[i] = (const short8*)(As + r  * 32 + ((q ^ ((r  >> 1) & 3)) * 8));
    bp[i] = (const short8*)(Bs + rn * 32 + ((q ^ ((rn >> 1) & 3)) * 8));
  }
  auto* As3 = (__attribute__((address_space(3))) ushort_t*)As;
  auto* Bs3 = (__attribute__((address_space(3))) ushort_t*)Bs;
  floatx4 acc[4][4] = {};
  for (int k0 = 0; k0 < DD; k0 += 32) {
    __syncthreads();
#pragma unroll
    for (int j = 0; j < 2; j++) {
      int e = t + j * 256;
      int row = e >> 2, slot = e & 3;
      int c = slot ^ ((row >> 1) & 3);
      const ushort_t* asrc = A + (size_t)(m0 + row) * DD + k0 + c * 8;
      const ushort_t* wsrc = W + (size_t)(n0 + row) * DD + k0 + c * 8;
      __builtin_amdgcn_global_load_lds(
          (const __attribute__((address_space(1))) unsigned*)asrc,
          (__attribute__((address_space(3))) unsigned*)(As3 + e * 8), 16, 0, 0);
      __builtin_amdgcn_global_load_lds(
          (const __attribute__((address_space(1))) unsigned*)wsrc,
          (__attribute__((address_space(3))) unsigned*)(Bs3 + e * 8), 16, 0, 0);
    }
    __syncthreads();
    short8 af[4], bf[4];
#pragma unroll
    for (int i = 0; i < 4; i++) { af[i] = *ap[i]; bf[i] = *bp[i]; }
#pragma unroll
    for (int i = 0; i < 4; i++)
#pragma unroll
      for (int j = 0; j < 4; j++)
        acc[i][j] = __builtin_amdgcn_mfma_f32_16x16x32_bf16(af[i], bf[j], acc[i][j], 0, 0, 0);
  }
  int orow = m0 + wm + q * 4;
  int ocol = n0 + wn + fr;
  if (mode == 1) {
    int seg = n0 >> 10;
    ushort_t* Cb = (ushort_t*)Cout + (size_t)seg * MD;
#pragma unroll
    for (int i = 0; i < 4; i++)
#pragma unroll
      for (int j = 0; j < 4; j++)
#pragma unroll
        for (int rr = 0; rr < 4; rr++)
          Cb[(size_t)(orow + i * 16 + rr) * DD + ((ocol + j * 16) & 1023)] =
              f2bf(acc[i][j][rr]);
  } else {  // mode 2: fc epilogue
    float* C = (float*)Cout;
#pragma unroll
    for (int j = 0; j < 4; j++) {
      int colg = ocol + j * 16;
      float bv = bias[colg];
#pragma unroll
      for (int i = 0; i < 4; i++)
#pragma unroll
        for (int rr = 0; rr < 4; rr++) {
          size_t idx = (size_t)(orow + i * 16 + rr) * DD + colg;
          C[idx] = fmaxf(acc[i][j][rr] + bv, 0.f) + lnres[idx];
        }
    }
  }
}

// Flash attention, bf16 MFMA. Block: 64 q rows of one (b,h); wave w owns
// q rows [w*16, w*16+16). K chunks of 64 keys. Q,K natural [row][dh] LDS
// (XOR chunk swizzle); V transposed [dh][key] LDS. Online softmax state in
// registers. P LDS round-trip to A-operand layout. cross=1: K/V layout
// (B,H,T,DH) + triangular chunk skip + diagonal-chunk mask.
// Output: resid + O, fp32.
__global__ __launch_bounds__(256) void attn_mfma_k(const ushort_t* __restrict__ Qb,
                                                   const ushort_t* __restrict__ Kb,
                                                   const ushort_t* __restrict__ Vb,
                                                   const float* __restrict__ resid,
                                                   float* __restrict__ out,
                                                   int cross) {
  __shared__ ushort_t Qs[64 * 64];
  __shared__ ushort_t Ks[64 * 64];
  __shared__ ushort_t Vts[64 * 64];
  __shared__ ushort_t Ps[4 * 16 * 64];
  int t = threadIdx.x, lane = t & 63, w = t >> 6;
  int fr = lane & 15, q8 = lane >> 4;
  int qt = blockIdx.x, bh = blockIdx.y;
  int b = bh >> 4, h = bh & 15;
  size_t qbase = ((size_t)(b * TT + qt * 64)) * DD + h * DHH;
  size_t kvbase; int kvstride;
  if (cross) { kvbase = (size_t)bh * TT * DHH;          kvstride = DHH; }
  else       { kvbase = (size_t)b * TT * DD + h * DHH;  kvstride = DD;  }

  auto* Qs3  = (__attribute__((address_space(3))) ushort_t*)Qs;
  auto* Ks3  = (__attribute__((address_space(3))) ushort_t*)Ks;

  // stage Q tile (64 rows x 8 chunks of 8 bf16), source-side swizzle
#pragma unroll
  for (int j = 0; j < 2; j++) {
    int e = t + j * 256;
    int row = e >> 3, slot = e & 7;
    int c = slot ^ (row & 7);
    const ushort_t* src = Qb + qbase + (size_t)row * DD + c * 8;
    __builtin_amdgcn_global_load_lds(
        (const __attribute__((address_space(1))) unsigned*)src,
        (__attribute__((address_space(3))) unsigned*)(Qs3 + e * 8), 16, 0, 0);
  }
  __syncthreads();

  // Q A-fragments: lane holds Q[w*16 + fr][q8*8 + ks*32 .. +8]
  short8 qf[2];
#pragma unroll
  for (int ks = 0; ks < 2; ks++) {
    int row = w * 16 + fr;
    int slot = (ks * 4 + q8) ^ (row & 7);
    qf[ks] = *(const short8*)(Qs + row * 64 + slot * 8);
  }

  float m_i[4], l_i[4];
  floatx4 o_acc[4] = {};
#pragma unroll
  for (int r = 0; r < 4; r++) { m_i[r] = -1e30f; l_i[r] = 0.f; }

  int nch = cross ? (qt + 1) : 8;
  for (int ch = 0; ch < nch; ch++) {
    __syncthreads();   // prior chunk's K/V reads done
    // stage K chunk
#pragma unroll
    for (int j = 0; j < 2; j++) {
      int e = t + j * 256;
      int row = e >> 3, slot = e & 7;
      int c = slot ^ (row & 7);
      const ushort_t* src = Kb + kvbase + (size_t)(ch * 64 + row) * kvstride + c * 8;
      __builtin_amdgcn_global_load_lds(
          (const __attribute__((address_space(1))) unsigned*)src,
          (__attribute__((address_space(3))) unsigned*)(Ks3 + e * 8), 16, 0, 0);
    }
    // stage V transposed: thread owns keys {2kp,2kp+1} x 8 dh
    {
      int kp = t & 31, dhg = (t >> 5) * 8;
      const ushort_t* v0 = Vb + kvbase + (size_t)(ch * 64 + 2 * kp) * kvstride + dhg;
      short8 a0 = *(const short8*)v0;
      short8 a1 = *(const short8*)(v0 + kvstride);
#pragma unroll
      for (int j = 0; j < 8; j++) {
        int dh = dhg + j;
        int slot = (kp >> 2) ^ (dh & 7);
        unsigned pk = (unsigned)(unsigned short)a0[j] |
                      ((unsigned)(unsigned short)a1[j] << 16);
        *(unsigned*)(Vts + dh * 64 + slot * 8 + (kp & 3) * 2) = pk;
      }
    }
    __syncthreads();

    // S = Q K^T (per wave: 16 q x 64 keys), scale, mask
    floatx4 s[4] = {};
    __builtin_amdgcn_s_setprio(1);
#pragma unroll
    for (int nt = 0; nt < 4; nt++) {
      int key = nt * 16 + fr;
#pragma unroll
      for (int ks = 0; ks < 2; ks++) {
        int slot = (ks * 4 + q8) ^ (key & 7);
        short8 kf = *(const short8*)(Ks + key * 64 + slot * 8);
        s[nt] = __builtin_amdgcn_mfma_f32_16x16x32_bf16(qf[ks], kf, s[nt], 0, 0, 0);
      }
    }
    __builtin_amdgcn_s_setprio(0);
    float sv[4][4];
#pragma unroll
    for (int nt = 0; nt < 4; nt++)
#pragma unroll
      for (int r = 0; r < 4; r++)
        sv[nt][r] = s[nt][r] * INV_RD;
    if (cross && ch == qt) {
#pragma unroll
      for (int nt = 0; nt < 4; nt++) {
        int key_g = ch * 64 + nt * 16 + fr;
#pragma unroll
        for (int r = 0; r < 4; r++) {
          int q_g = qt * 64 + w * 16 + q8 * 4 + r;
          if (key_g > q_g) sv[nt][r] = -1e30f;
        }
      }
    }

    // online softmax update (rows = q8*4+r, reduce across fr lanes)
    float pv[4][4];
#pragma unroll
    for (int r = 0; r < 4; r++) {
      float mch = fmaxf(fmaxf(sv[0][r], sv[1][r]), fmaxf(sv[2][r], sv[3][r]));
#pragma unroll
      for (int off = 1; off < 16; off <<= 1) mch = fmaxf(mch, __shfl_xor(mch, off));
      float mn = fmaxf(m_i[r], mch);
      float alpha = __expf(m_i[r] - mn);
      m_i[r] = mn;
      float rs = 0.f;
#pragma unroll
      for (int nt = 0; nt < 4; nt++) {
        float pe = __expf(sv[nt][r] - mn);
        pv[nt][r] = pe; rs += pe;
      }
#pragma unroll
      for (int off = 1; off < 16; off <<= 1) rs += __shfl_xor(rs, off);
      l_i[r] = l_i[r] * alpha + rs;
#pragma unroll
      for (int nt = 0; nt < 4; nt++) o_acc[nt][r] *= alpha;
    }

    // P -> LDS (wave-private), C-layout -> A-layout round trip
    ushort_t* Pw = Ps + w * 1024;
#pragma unroll
    for (int nt = 0; nt < 4; nt++) {
      int col = nt * 16 + fr;
#pragma unroll
      for (int r = 0; r < 4; r++) {
        int row = q8 * 4 + r;
        int slot = (col >> 3) ^ (row & 7);
        Pw[row * 64 + slot * 8 + (col & 7)] = f2bf(pv[nt][r]);
      }
    }
    short8 pf[2];
#pragma unroll
    for (int ks = 0; ks < 2; ks++) {
      int slot = (ks * 4 + q8) ^ (fr & 7);
      pf[ks] = *(const short8*)(Pw + fr * 64 + slot * 8);
    }
    // O += P V  (B-fragment from transposed V)
    __builtin_amdgcn_s_setprio(1);
#pragma unroll
    for (int nt = 0; nt < 4; nt++) {
      int dh = nt * 16 + fr;
#pragma unroll
      for (int ks = 0; ks < 2; ks++) {
        int slot = (ks * 4 + q8) ^ (dh & 7);
        short8 vf = *(const short8*)(Vts + dh * 64 + slot * 8);
        o_acc[nt] = __builtin_amdgcn_mfma_f32_16x16x32_bf16(pf[ks], vf, o_acc[nt], 0, 0, 0);
      }
    }
    __builtin_amdgcn_s_setprio(0);
  }

  // epilogue: O/l + residual
  float invl[4];
#pragma unroll
  for (int r = 0; r < 4; r++) invl[r] = 1.0f / l_i[r];
#pragma unroll
  for (int nt = 0; nt < 4; nt++) {
#pragma unroll
    for (int r = 0; r < 4; r++) {
      size_t row_g = (size_t)(b * TT + qt * 64 + w * 16 + q8 * 4 + r);
      size_t idx = row_g * DD + h * DHH + nt * 16 + fr;
      out[idx] = resid[idx] + o_acc[nt][r] * invl[r];
    }
  }
}

// Ordinal sigmoid head.
__global__ __launch_bounds__(256) void head_k(const float* __restrict__ x,
                                              const float* __restrict__ cut,
                                              float* __restrict__ out) {
  __shared__ float obuf[2560];
  int t = threadIdx.x;
  size_t e = (size_t)blockIdx.x * 256 + t;
  float xv = x[e];
  float bj = cut[0];
  float sprev = 1.0f / (1.0f + __expf(xv - bj));
  obuf[t * 10 + 0] = sprev;
#pragma unroll
  for (int j = 1; j < 9; j++) {
    float cj = cut[j];
    bj += cj * cj;
    float sj = 1.0f / (1.0f + __expf(xv - bj));
    obuf[t * 10 + j] = sj - sprev;
    sprev = sj;
  }
  obuf[t * 10 + 9] = 1.0f - sprev;
  __syncthreads();
  size_t base = (size_t)blockIdx.x * 2560;
#pragma unroll
  for (int r = 0; r < 10; r++) out[base + r * 256 + t] = obuf[r * 256 + t];
}

extern "C" void kernel_launch(void* const* d_in, const int* in_sizes, int n_in,
                              void* d_out, int out_size, void* d_ws, size_t ws_size,
                              hipStream_t stream) {
  (void)in_sizes; (void)n_in; (void)out_size; (void)ws_size;
  const float* x    = (const float*)d_in[0];
  const float* kin  = (const float*)d_in[1];
  const float* vin  = (const float*)d_in[2];
  const float* pos  = (const float*)d_in[3];
  const float* Wq1  = (const float*)d_in[4];
  const float* Wk1  = (const float*)d_in[5];
  const float* Wv1  = (const float*)d_in[6];
  const float* Wq2  = (const float*)d_in[7];
  const float* Wfc  = (const float*)d_in[8];
  const float* bfc  = (const float*)d_in[9];
  const float* g1   = (const float*)d_in[10];
  const float* b1   = (const float*)d_in[11];
  const float* g2   = (const float*)d_in[12];
  const float* b2   = (const float*)d_in[13];
  const float* g3   = (const float*)d_in[14];
  const float* b3   = (const float*)d_in[15];
  const float* cut  = (const float*)d_in[16];
  float* out = (float*)d_out;

  // ws (120 MB): cur 16 | tmp 16 | act_bf 8 | qkv_bf 24 | kinbf 8 | vinbf 8
  //              | wqkv 24 | wq2 8 | wfc 8
  float* cur = (float*)d_ws;
  float* tmp = cur + MD;
  ushort_t* act_bf = (ushort_t*)(tmp + MD);
  ushort_t* qbf    = act_bf + MD;     // qkv_bf base: q | k | v contiguous
  ushort_t* kbf    = qbf + MD;
  ushort_t* vbf    = kbf + MD;
  ushort_t* kinbf  = vbf + MD;
  ushort_t* vinbf  = kinbf + MD;
  ushort_t* wqkv   = vinbf + MD;                               // [L][3072][1024]
  ushort_t* wq2    = wqkv + (size_t)LLAY * 3 * DD * DD;        // [L][1024][1024]
  ushort_t* wfc    = wq2  + (size_t)LLAY * DD * DD;

  dim3 b256(256);
  dim3 gqkv(3 * DD / 128, MM / 128);  // (24, 32) = 768 blocks, 3/CU
  dim3 gg(DD / 128, MM / 128);        // (8, 32)
  dim3 ga(TT / 64, BB * HH);          // (8, 128)

  cast_all_k<<<7 * 4096, b256, 0, stream>>>(Wq1, Wk1, Wv1, Wq2, Wfc, kin, vin,
                                            wqkv, wq2, wfc, kinbf, vinbf);

  add_pos_k<<<MD / 1024, b256, 0, stream>>>(x, pos, cur, act_bf);

  for (int i = 0; i < LLAY; i++) {
    const float* attn_in;
    if (i) {
      ln_k<<<MM, b256, 0, stream>>>(cur, tmp, act_bf,
                                    g1 + (size_t)(i - 1) * DD, b1 + (size_t)(i - 1) * DD);
      attn_in = tmp;
    } else {
      attn_in = cur;   // act_bf already holds bf16(cur)
    }
    // fused QKV GEMM: N=3072, outputs routed to qbf/kbf/vbf
    gemm_mfma_bt_k<<<gqkv, b256, 0, stream>>>(act_bf, wqkv + (size_t)i * 3 * DD * DD,
                                              qbf, nullptr, nullptr, 1);
    attn_mfma_k<<<ga, b256, 0, stream>>>(qbf, kbf, vbf, attn_in, cur, 0);

    ln_k<<<MM, b256, 0, stream>>>(cur, tmp, act_bf,
                                  g2 + (size_t)i * DD, b2 + (size_t)i * DD);
    gemm_mfma_bt_k<<<gg, b256, 0, stream>>>(act_bf, wq2 + (size_t)i * DD * DD,
                                            qbf, nullptr, nullptr, 1);
    attn_mfma_k<<<ga, b256, 0, stream>>>(qbf, kinbf, vinbf, tmp, cur, 1);

    ln_k<<<MM, b256, 0, stream>>>(cur, tmp, act_bf,
                                  g3 + (size_t)i * DD, b3 + (size_t)i * DD);
    // fc GEMM with fused bias+relu+residual epilogue -> cur (fp32)
    gemm_mfma_bt_k<<<gg, b256, 0, stream>>>(act_bf, wfc + (size_t)i * DD * DD,
                                            cur, bfc + (size_t)i * DD, tmp, 2);
  }

  head_k<<<MD / 256, b256, 0, stream>>>(cur, cut, out);
}

// Round 2
// 978.888 us; speedup vs baseline: 1.2961x; 1.1845x over previous
//
#include <hip/hip_runtime.h>

// ---------------------------------------------------------------------------
// Decoder: B=8 T=512 D=1024 H=16 DH=64 L=4 C=10.
// Round 4: occupancy + locality pass.
//  - gemm64: BM=128/BN=64 GEMM for N=1024 (Wq2, fc) -> 512 blocks = 2/CU
//    (vs 256 = 1/CU), barrier drains covered by independent blocks.
//  - XCD-bijective swizzle (d%8 chunking) on attn + both GEMMs: same-bh
//    q-tiles share one XCD's L2 (K/V slices L2-resident); GEMM A-panels
//    L2-resident per XCD.
//  - add_pos merged into cast_all (segment 7): one fewer dispatch.
// Workspace (120 MB): cur 16 | tmp 16 | act_bf 8 | qkv_bf 24 | kinbf 8 |
//                     vinbf 8 | wqkv 24 | wq2 8 | wfc 8
// ---------------------------------------------------------------------------

#define BB   8
#define TT   512
#define DD   1024
#define HH   16
#define DHH  64
#define LLAY 4
#define MM   (BB*TT)          // 4096 rows
#define MD   ((size_t)MM*DD)  // 4,194,304 elements
#define INV_RD (1.0f/32.0f)   // 1/sqrt(D)
#define LNEPS 1e-5f

typedef unsigned short ushort_t;
typedef __attribute__((ext_vector_type(8))) short short8;
typedef __attribute__((ext_vector_type(4))) float floatx4;

__device__ inline ushort_t f2bf(float f) {
  unsigned u = __builtin_bit_cast(unsigned, f);
  unsigned r = (u + 0x7FFFu + ((u >> 16) & 1u)) >> 16;  // RNE
  return (ushort_t)r;
}

// One kernel, 8 segments of 4M fp32 elements each (1M float4 / segment):
//  seg 0..2 : Wq1/Wk1/Wv1 [L,1024,1024] -> fused wqkv [L][3072][1024]
//  seg 3,4  : Wq2, Wfc -> linear bf16
//  seg 5,6  : kin, vin -> linear bf16
//  seg 7    : x + pos -> cur (fp32) + act_bf (bf16)
__global__ __launch_bounds__(256) void cast_all_k(
    const float* __restrict__ Wq1, const float* __restrict__ Wk1,
    const float* __restrict__ Wv1, const float* __restrict__ Wq2f,
    const float* __restrict__ Wfcf, const float* __restrict__ kin,
    const float* __restrict__ vin, const float* __restrict__ x,
    const float* __restrict__ pos,
    ushort_t* __restrict__ wqkv, ushort_t* __restrict__ wq2,
    ushort_t* __restrict__ wfc, ushort_t* __restrict__ kinbf,
    ushort_t* __restrict__ vinbf, float* __restrict__ cur,
    ushort_t* __restrict__ act_bf) {
  int seg = blockIdx.x >> 12;
  size_t j = ((size_t)(blockIdx.x & 4095)) * 256 + threadIdx.x;  // float4 idx
  if (seg == 7) {
    int dq  = (int)(j & 255);
    int row = (int)(j >> 8);
    int t   = row & (TT - 1);
    float4 a = ((const float4*)x)[j];
    float4 p = ((const float4*)pos)[(size_t)t * 256 + dq];
    a.x += p.x; a.y += p.y; a.z += p.z; a.w += p.w;
    ((float4*)cur)[j] = a;
    ushort4 b; b.x = f2bf(a.x); b.y = f2bf(a.y); b.z = f2bf(a.z); b.w = f2bf(a.w);
    ((ushort4*)act_bf)[j] = b;
    return;
  }
  const float* src;
  switch (seg) {
    case 0: src = Wq1; break;
    case 1: src = Wk1; break;
    case 2: src = Wv1; break;
    case 3: src = Wq2f; break;
    case 4: src = Wfcf; break;
    case 5: src = kin; break;
    default: src = vin; break;
  }
  float4 v = ((const float4*)src)[j];
  ushort4 o; o.x = f2bf(v.x); o.y = f2bf(v.y); o.z = f2bf(v.z); o.w = f2bf(v.w);
  if (seg < 3) {
    int d4 = (int)(j & 255);
    int n  = (int)((j >> 8) & 1023);
    int i  = (int)(j >> 18);
    size_t drow = (size_t)i * 3072 + (size_t)seg * 1024 + n;
    ((ushort4*)wqkv)[drow * 256 + d4] = o;
  } else {
    ushort_t* dst = (seg == 3) ? wq2 : (seg == 4) ? wfc : (seg == 5) ? kinbf : vinbf;
    ((ushort4*)dst)[j] = o;
  }
}

// LayerNorm: one block per row of D=1024; writes fp32 + bf16 copies.
__global__ __launch_bounds__(256) void ln_k(const float* __restrict__ in,
                                            float* __restrict__ out,
                                            ushort_t* __restrict__ out_bf,
                                            const float* __restrict__ g,
                                            const float* __restrict__ bt) {
  int row = blockIdx.x;
  int t = threadIdx.x;
  const float4* r4 = (const float4*)(in + (size_t)row * DD);
  float4 v = r4[t];
  float s  = v.x + v.y + v.z + v.w;
  float ss = v.x*v.x + v.y*v.y + v.z*v.z + v.w*v.w;
#pragma unroll
  for (int off = 32; off > 0; off >>= 1) {
    s  += __shfl_down(s, off);
    ss += __shfl_down(ss, off);
  }
  __shared__ float red[8];
  int w = t >> 6;
  if ((t & 63) == 0) { red[w] = s; red[4 + w] = ss; }
  __syncthreads();
  s  = red[0] + red[1] + red[2] + red[3];
  ss = red[4] + red[5] + red[6] + red[7];
  float mean = s * (1.0f / DD);
  float var  = ss * (1.0f / DD) - mean * mean;
  float inv  = rsqrtf(var + LNEPS);
  float4 gv = ((const float4*)g)[t];
  float4 bv = ((const float4*)bt)[t];
  float4 o;
  o.x = (v.x - mean) * inv * gv.x + bv.x;
  o.y = (v.y - mean) * inv * gv.y + bv.y;
  o.z = (v.z - mean) * inv * gv.z + bv.z;
  o.w = (v.w - mean) * inv * gv.w + bv.w;
  ((float4*)(out + (size_t)row * DD))[t] = o;
  ushort4 ob; ob.x = f2bf(o.x); ob.y = f2bf(o.y); ob.z = f2bf(o.z); ob.w = f2bf(o.w);
  ((ushort4*)(out_bf + (size_t)row * DD))[t] = ob;
}

// 128x128 tile GEMM (m97 structure): C[m,n] = sum_k A[m,k]*W[n,k].
// Used for the fused QKV GEMM (N=3072): bf16 out, 1024-col segments routed
// to contiguous [MM,DD] buffers at Cout + seg*MD. 1D grid, XCD-bijective
// swizzle (nwg = nbx*nby must be %8==0).
__global__ __launch_bounds__(256) void gemm_mfma_bt_k(const ushort_t* __restrict__ A,
                                                      const ushort_t* __restrict__ W,
                                                      ushort_t* __restrict__ Cout,
                                                      int nbx) {
  __shared__ ushort_t As[128 * 32];
  __shared__ ushort_t Bs[128 * 32];
  int t = threadIdx.x;
  int d = blockIdx.x;
  int chunk = gridDim.x >> 3;
  int logical = (d & 7) * chunk + (d >> 3);
  int bx = logical % nbx, by = logical / nbx;
  int n0 = bx * 128, m0 = by * 128;
  int lane = t & 63, w = t >> 6;
  int wm = (w >> 1) * 64, wn = (w & 1) * 64;
  int fr = lane & 15, q = lane >> 4;
  const short8* ap[4]; const short8* bp[4];
#pragma unroll
  for (int i = 0; i < 4; i++) {
    int r  = wm + i * 16 + fr;
    int rn = wn + i * 16 + fr;
    ap[i] = (const short8*)(As + r  * 32 + ((q ^ ((r  >> 1) & 3)) * 8));
    bp[i] = (const short8*)(Bs + rn * 32 + ((q ^ ((rn >> 1) & 3)) * 8));
  }
  auto* As3 = (__attribute__((address_space(3))) ushort_t*)As;
  auto* Bs3 = (__attribute__((address_space(3))) ushort_t*)Bs;
  floatx4 acc[4][4] = {};
  for (int k0 = 0; k0 < DD; k0 += 32) {
    __syncthreads();
#pragma unroll
    for (int j = 0; j < 2; j++) {
      int e = t + j * 256;
      int row = e >> 2, slot = e & 3;
      int c = slot ^ ((row >> 1) & 3);
      const ushort_t* asrc = A + (size_t)(m0 + row) * DD + k0 + c * 8;
      const ushort_t* wsrc = W + (size_t)(n0 + row) * DD + k0 + c * 8;
      __builtin_amdgcn_global_load_lds(
          (const __attribute__((address_space(1))) unsigned*)asrc,
          (__attribute__((address_space(3))) unsigned*)(As3 + e * 8), 16, 0, 0);
      __builtin_amdgcn_global_load_lds(
          (const __attribute__((address_space(1))) unsigned*)wsrc,
          (__attribute__((address_space(3))) unsigned*)(Bs3 + e * 8), 16, 0, 0);
    }
    __syncthreads();
    short8 af[4], bf[4];
#pragma unroll
    for (int i = 0; i < 4; i++) { af[i] = *ap[i]; bf[i] = *bp[i]; }
#pragma unroll
    for (int i = 0; i < 4; i++)
#pragma unroll
      for (int j = 0; j < 4; j++)
        acc[i][j] = __builtin_amdgcn_mfma_f32_16x16x32_bf16(af[i], bf[j], acc[i][j], 0, 0, 0);
  }
  int orow = m0 + wm + q * 4;
  int ocol = n0 + wn + fr;
  int seg = n0 >> 10;
  ushort_t* Cb = Cout + (size_t)seg * MD;
#pragma unroll
  for (int i = 0; i < 4; i++)
#pragma unroll
    for (int j = 0; j < 4; j++)
#pragma unroll
      for (int rr = 0; rr < 4; rr++)
        Cb[(size_t)(orow + i * 16 + rr) * DD + ((ocol + j * 16) & 1023)] =
            f2bf(acc[i][j][rr]);
}

// 128x64 tile GEMM for N=1024 (grid 512 = 2 blocks/CU).
// mode 1: bf16 out. mode 2: fp32 fc epilogue C = relu(acc+bias)+lnres.
__global__ __launch_bounds__(256) void gemm64_k(const ushort_t* __restrict__ A,
                                                const ushort_t* __restrict__ W,
                                                void* __restrict__ Cout,
                                                const float* __restrict__ bias,
                                                const float* __restrict__ lnres,
                                                int mode) {
  __shared__ ushort_t As[128 * 32];
  __shared__ ushort_t Bs[64 * 32];
  int t = threadIdx.x;
  int d = blockIdx.x;                 // nwg = 512, chunk = 64
  int logical = (d & 7) * 64 + (d >> 3);
  int bx = logical & 15, by = logical >> 4;   // nbx=16 (n), nby=32 (m)
  int n0 = bx * 64, m0 = by * 128;
  int lane = t & 63, w = t >> 6;
  int wm = (w >> 1) * 64, wn = (w & 1) * 32;
  int fr = lane & 15, q = lane >> 4;
  const short8* ap[4]; const short8* bp[2];
#pragma unroll
  for (int i = 0; i < 4; i++) {
    int r = wm + i * 16 + fr;
    ap[i] = (const short8*)(As + r * 32 + ((q ^ ((r >> 1) & 3)) * 8));
  }
#pragma unroll
  for (int j = 0; j < 2; j++) {
    int rn = wn + j * 16 + fr;
    bp[j] = (const short8*)(Bs + rn * 32 + ((q ^ ((rn >> 1) & 3)) * 8));
  }
  auto* As3 = (__attribute__((address_space(3))) ushort_t*)As;
  auto* Bs3 = (__attribute__((address_space(3))) ushort_t*)Bs;
  floatx4 acc[4][2] = {};
  for (int k0 = 0; k0 < DD; k0 += 32) {
    __syncthreads();
#pragma unroll
    for (int j = 0; j < 2; j++) {
      int e = t + j * 256;
      int row = e >> 2, slot = e & 3;
      int c = slot ^ ((row >> 1) & 3);
      const ushort_t* asrc = A + (size_t)(m0 + row) * DD + k0 + c * 8;
      __builtin_amdgcn_global_load_lds(
          (const __attribute__((address_space(1))) unsigned*)asrc,
          (__attribute__((address_space(3))) unsigned*)(As3 + e * 8), 16, 0, 0);
    }
    {
      int e = t;
      int row = e >> 2, slot = e & 3;
      int c = slot ^ ((row >> 1) & 3);
      const ushort_t* wsrc = W + (size_t)(n0 + row) * DD + k0 + c * 8;
      __builtin_amdgcn_global_load_lds(
          (const __attribute__((address_space(1))) unsigned*)wsrc,
          (__attribute__((address_space(3))) unsigned*)(Bs3 + e * 8), 16, 0, 0);
    }
    __syncthreads();
    short8 af[4], bf[2];
#pragma unroll
    for (int i = 0; i < 4; i++) af[i] = *ap[i];
#pragma unroll
    for (int j = 0; j < 2; j++) bf[j] = *bp[j];
#pragma unroll
    for (int i = 0; i < 4; i++)
#pragma unroll
      for (int j = 0; j < 2; j++)
        acc[i][j] = __builtin_amdgcn_mfma_f32_16x16x32_bf16(af[i], bf[j], acc[i][j], 0, 0, 0);
  }
  int orow = m0 + wm + q * 4;
  if (mode == 1) {
    ushort_t* Cb = (ushort_t*)Cout;
#pragma unroll
    for (int i = 0; i < 4; i++)
#pragma unroll
      for (int j = 0; j < 2; j++) {
        int colg = n0 + wn + j * 16 + fr;
#pragma unroll
        for (int rr = 0; rr < 4; rr++)
          Cb[(size_t)(orow + i * 16 + rr) * DD + colg] = f2bf(acc[i][j][rr]);
      }
  } else {  // fc epilogue
    float* C = (float*)Cout;
#pragma unroll
    for (int j = 0; j < 2; j++) {
      int colg = n0 + wn + j * 16 + fr;
      float bv = bias[colg];
#pragma unroll
      for (int i = 0; i < 4; i++)
#pragma unroll
        for (int rr = 0; rr < 4; rr++) {
          size_t idx = (size_t)(orow + i * 16 + rr) * DD + colg;
          C[idx] = fmaxf(acc[i][j][rr] + bv, 0.f) + lnres[idx];
        }
    }
  }
}

// Flash attention, bf16 MFMA. 1D grid of 1024 with XCD-bijective swizzle:
// XCD x owns bh in [x*16, x*16+16), all 8 q-tiles -> K/V slices L2-resident.
// Block: 64 q rows of one (b,h); wave w owns q rows [w*16, w*16+16).
// K chunks of 64 keys. Q,K natural [row][dh] LDS (XOR chunk swizzle);
// V transposed [dh][key] LDS. Online softmax in registers. P LDS round
// trip. cross=1: K/V layout (B,H,T,DH) + triangular skip + diagonal mask.
__global__ __launch_bounds__(256) void attn_mfma_k(const ushort_t* __restrict__ Qb,
                                                   const ushort_t* __restrict__ Kb,
                                                   const ushort_t* __restrict__ Vb,
                                                   const float* __restrict__ resid,
                                                   float* __restrict__ out,
                                                   int cross) {
  __shared__ ushort_t Qs[64 * 64];
  __shared__ ushort_t Ks[64 * 64];
  __shared__ ushort_t Vts[64 * 64];
  __shared__ ushort_t Ps[4 * 16 * 64];
  int t = threadIdx.x, lane = t & 63, w = t >> 6;
  int fr = lane & 15, q8 = lane >> 4;
  int dsp = blockIdx.x;                       // nwg = 1024, chunk = 128
  int logical = (dsp & 7) * 128 + (dsp >> 3);
  int qt = logical & 7, bh = logical >> 3;
  int b = bh >> 4, h = bh & 15;
  size_t qbase = ((size_t)(b * TT + qt * 64)) * DD + h * DHH;
  size_t kvbase; int kvstride;
  if (cross) { kvbase = (size_t)bh * TT * DHH;          kvstride = DHH; }
  else       { kvbase = (size_t)b * TT * DD + h * DHH;  kvstride = DD;  }

  auto* Qs3  = (__attribute__((address_space(3))) ushort_t*)Qs;
  auto* Ks3  = (__attribute__((address_space(3))) ushort_t*)Ks;

  // stage Q tile (64 rows x 8 chunks of 8 bf16), source-side swizzle
#pragma unroll
  for (int j = 0; j < 2; j++) {
    int e = t + j * 256;
    int row = e >> 3, slot = e & 7;
    int c = slot ^ (row & 7);
    const ushort_t* src = Qb + qbase + (size_t)row * DD + c * 8;
    __builtin_amdgcn_global_load_lds(
        (const __attribute__((address_space(1))) unsigned*)src,
        (__attribute__((address_space(3))) unsigned*)(Qs3 + e * 8), 16, 0, 0);
  }
  __syncthreads();

  // Q A-fragments: lane holds Q[w*16 + fr][q8*8 + ks*32 .. +8]
  short8 qf[2];
#pragma unroll
  for (int ks = 0; ks < 2; ks++) {
    int row = w * 16 + fr;
    int slot = (ks * 4 + q8) ^ (row & 7);
    qf[ks] = *(const short8*)(Qs + row * 64 + slot * 8);
  }

  float m_i[4], l_i[4];
  floatx4 o_acc[4] = {};
#pragma unroll
  for (int r = 0; r < 4; r++) { m_i[r] = -1e30f; l_i[r] = 0.f; }

  int nch = cross ? (qt + 1) : 8;
  for (int ch = 0; ch < nch; ch++) {
    __syncthreads();   // prior chunk's K/V reads done
    // stage K chunk
#pragma unroll
    for (int j = 0; j < 2; j++) {
      int e = t + j * 256;
      int row = e >> 3, slot = e & 7;
      int c = slot ^ (row & 7);
      const ushort_t* src = Kb + kvbase + (size_t)(ch * 64 + row) * kvstride + c * 8;
      __builtin_amdgcn_global_load_lds(
          (const __attribute__((address_space(1))) unsigned*)src,
          (__attribute__((address_space(3))) unsigned*)(Ks3 + e * 8), 16, 0, 0);
    }
    // stage V transposed: thread owns keys {2kp,2kp+1} x 8 dh
    {
      int kp = t & 31, dhg = (t >> 5) * 8;
      const ushort_t* v0 = Vb + kvbase + (size_t)(ch * 64 + 2 * kp) * kvstride + dhg;
      short8 a0 = *(const short8*)v0;
      short8 a1 = *(const short8*)(v0 + kvstride);
#pragma unroll
      for (int j = 0; j < 8; j++) {
        int dh = dhg + j;
        int slot = (kp >> 2) ^ (dh & 7);
        unsigned pk = (unsigned)(unsigned short)a0[j] |
                      ((unsigned)(unsigned short)a1[j] << 16);
        *(unsigned*)(Vts + dh * 64 + slot * 8 + (kp & 3) * 2) = pk;
      }
    }
    __syncthreads();

    // S = Q K^T (per wave: 16 q x 64 keys), scale, mask
    floatx4 s[4] = {};
    __builtin_amdgcn_s_setprio(1);
#pragma unroll
    for (int nt = 0; nt < 4; nt++) {
      int key = nt * 16 + fr;
#pragma unroll
      for (int ks = 0; ks < 2; ks++) {
        int slot = (ks * 4 + q8) ^ (key & 7);
        short8 kf = *(const short8*)(Ks + key * 64 + slot * 8);
        s[nt] = __builtin_amdgcn_mfma_f32_16x16x32_bf16(qf[ks], kf, s[nt], 0, 0, 0);
      }
    }
    __builtin_amdgcn_s_setprio(0);
    float sv[4][4];
#pragma unroll
    for (int nt = 0; nt < 4; nt++)
#pragma unroll
      for (int r = 0; r < 4; r++)
        sv[nt][r] = s[nt][r] * INV_RD;
    if (cross && ch == qt) {
#pragma unroll
      for (int nt = 0; nt < 4; nt++) {
        int key_g = ch * 64 + nt * 16 + fr;
#pragma unroll
        for (int r = 0; r < 4; r++) {
          int q_g = qt * 64 + w * 16 + q8 * 4 + r;
          if (key_g > q_g) sv[nt][r] = -1e30f;
        }
      }
    }

    // online softmax update (rows = q8*4+r, reduce across fr lanes)
    float pv[4][4];
#pragma unroll
    for (int r = 0; r < 4; r++) {
      float mch = fmaxf(fmaxf(sv[0][r], sv[1][r]), fmaxf(sv[2][r], sv[3][r]));
#pragma unroll
      for (int off = 1; off < 16; off <<= 1) mch = fmaxf(mch, __shfl_xor(mch, off));
      float mn = fmaxf(m_i[r], mch);
      float alpha = __expf(m_i[r] - mn);
      m_i[r] = mn;
      float rs = 0.f;
#pragma unroll
      for (int nt = 0; nt < 4; nt++) {
        float pe = __expf(sv[nt][r] - mn);
        pv[nt][r] = pe; rs += pe;
      }
#pragma unroll
      for (int off = 1; off < 16; off <<= 1) rs += __shfl_xor(rs, off);
      l_i[r] = l_i[r] * alpha + rs;
#pragma unroll
      for (int nt = 0; nt < 4; nt++) o_acc[nt][r] *= alpha;
    }

    // P -> LDS (wave-private), C-layout -> A-layout round trip
    ushort_t* Pw = Ps + w * 1024;
#pragma unroll
    for (int nt = 0; nt < 4; nt++) {
      int col = nt * 16 + fr;
#pragma unroll
      for (int r = 0; r < 4; r++) {
        int row = q8 * 4 + r;
        int slot = (col >> 3) ^ (row & 7);
        Pw[row * 64 + slot * 8 + (col & 7)] = f2bf(pv[nt][r]);
      }
    }
    short8 pf[2];
#pragma unroll
    for (int ks = 0; ks < 2; ks++) {
      int slot = (ks * 4 + q8) ^ (fr & 7);
      pf[ks] = *(const short8*)(Pw + fr * 64 + slot * 8);
    }
    // O += P V  (B-fragment from transposed V)
    __builtin_amdgcn_s_setprio(1);
#pragma unroll
    for (int nt = 0; nt < 4; nt++) {
      int dh = nt * 16 + fr;
#pragma unroll
      for (int ks = 0; ks < 2; ks++) {
        int slot = (ks * 4 + q8) ^ (dh & 7);
        short8 vf = *(const short8*)(Vts + dh * 64 + slot * 8);
        o_acc[nt] = __builtin_amdgcn_mfma_f32_16x16x32_bf16(pf[ks], vf, o_acc[nt], 0, 0, 0);
      }
    }
    __builtin_amdgcn_s_setprio(0);
  }

  // epilogue: O/l + residual
  float invl[4];
#pragma unroll
  for (int r = 0; r < 4; r++) invl[r] = 1.0f / l_i[r];
#pragma unroll
  for (int nt = 0; nt < 4; nt++) {
#pragma unroll
    for (int r = 0; r < 4; r++) {
      size_t row_g = (size_t)(b * TT + qt * 64 + w * 16 + q8 * 4 + r);
      size_t idx = row_g * DD + h * DHH + nt * 16 + fr;
      out[idx] = resid[idx] + o_acc[nt][r] * invl[r];
    }
  }
}

// Ordinal sigmoid head.
__global__ __launch_bounds__(256) void head_k(const float* __restrict__ x,
                                              const float* __restrict__ cut,
                                              float* __restrict__ out) {
  __shared__ float obuf[2560];
  int t = threadIdx.x;
  size_t e = (size_t)blockIdx.x * 256 + t;
  float xv = x[e];
  float bj = cut[0];
  float sprev = 1.0f / (1.0f + __expf(xv - bj));
  obuf[t * 10 + 0] = sprev;
#pragma unroll
  for (int j = 1; j < 9; j++) {
    float cj = cut[j];
    bj += cj * cj;
    float sj = 1.0f / (1.0f + __expf(xv - bj));
    obuf[t * 10 + j] = sj - sprev;
    sprev = sj;
  }
  obuf[t * 10 + 9] = 1.0f - sprev;
  __syncthreads();
  size_t base = (size_t)blockIdx.x * 2560;
#pragma unroll
  for (int r = 0; r < 10; r++) out[base + r * 256 + t] = obuf[r * 256 + t];
}

extern "C" void kernel_launch(void* const* d_in, const int* in_sizes, int n_in,
                              void* d_out, int out_size, void* d_ws, size_t ws_size,
                              hipStream_t stream) {
  (void)in_sizes; (void)n_in; (void)out_size; (void)ws_size;
  const float* x    = (const float*)d_in[0];
  const float* kin  = (const float*)d_in[1];
  const float* vin  = (const float*)d_in[2];
  const float* pos  = (const float*)d_in[3];
  const float* Wq1  = (const float*)d_in[4];
  const float* Wk1  = (const float*)d_in[5];
  const float* Wv1  = (const float*)d_in[6];
  const float* Wq2  = (const float*)d_in[7];
  const float* Wfc  = (const float*)d_in[8];
  const float* bfc  = (const float*)d_in[9];
  const float* g1   = (const float*)d_in[10];
  const float* b1   = (const float*)d_in[11];
  const float* g2   = (const float*)d_in[12];
  const float* b2   = (const float*)d_in[13];
  const float* g3   = (const float*)d_in[14];
  const float* b3   = (const float*)d_in[15];
  const float* cut  = (const float*)d_in[16];
  float* out = (float*)d_out;

  // ws (120 MB): cur 16 | tmp 16 | act_bf 8 | qkv_bf 24 | kinbf 8 | vinbf 8
  //              | wqkv 24 | wq2 8 | wfc 8
  float* cur = (float*)d_ws;
  float* tmp = cur + MD;
  ushort_t* act_bf = (ushort_t*)(tmp + MD);
  ushort_t* qbf    = act_bf + MD;     // qkv_bf base: q | k | v contiguous
  ushort_t* kbf    = qbf + MD;
  ushort_t* vbf    = kbf + MD;
  ushort_t* kinbf  = vbf + MD;
  ushort_t* vinbf  = kinbf + MD;
  ushort_t* wqkv   = vinbf + MD;                               // [L][3072][1024]
  ushort_t* wq2    = wqkv + (size_t)LLAY * 3 * DD * DD;        // [L][1024][1024]
  ushort_t* wfc    = wq2  + (size_t)LLAY * DD * DD;

  dim3 b256(256);

  cast_all_k<<<8 * 4096, b256, 0, stream>>>(Wq1, Wk1, Wv1, Wq2, Wfc, kin, vin,
                                            x, pos, wqkv, wq2, wfc, kinbf, vinbf,
                                            cur, act_bf);

  for (int i = 0; i < LLAY; i++) {
    const float* attn_in;
    if (i) {
      ln_k<<<MM, b256, 0, stream>>>(cur, tmp, act_bf,
                                    g1 + (size_t)(i - 1) * DD, b1 + (size_t)(i - 1) * DD);
      attn_in = tmp;
    } else {
      attn_in = cur;   // act_bf already holds bf16(cur)
    }
    // fused QKV GEMM: N=3072, outputs routed to qbf/kbf/vbf; 768 blocks
    gemm_mfma_bt_k<<<768, b256, 0, stream>>>(act_bf, wqkv + (size_t)i * 3 * DD * DD,
                                             qbf, 24);
    attn_mfma_k<<<1024, b256, 0, stream>>>(qbf, kbf, vbf, attn_in, cur, 0);

    ln_k<<<MM, b256, 0, stream>>>(cur, tmp, act_bf,
                                  g2 + (size_t)i * DD, b2 + (size_t)i * DD);
    gemm64_k<<<512, b256, 0, stream>>>(act_bf, wq2 + (size_t)i * DD * DD,
                                       qbf, nullptr, nullptr, 1);
    attn_mfma_k<<<1024, b256, 0, stream>>>(qbf, kinbf, vinbf, tmp, cur, 1);

    ln_k<<<MM, b256, 0, stream>>>(cur, tmp, act_bf,
                                  g3 + (size_t)i * DD, b3 + (size_t)i * DD);
    // fc GEMM with fused bias+relu+residual epilogue -> cur (fp32)
    gemm64_k<<<512, b256, 0, stream>>>(act_bf, wfc + (size_t)i * DD * DD,
                                       cur, bfc + (size_t)i * DD, tmp, 2);
  }

  head_k<<<MD / 256, b256, 0, stream>>>(cur, cut, out);
}